// Round 2
// baseline (134.145 us; speedup 1.0000x reference)
//
#include <hip/hip_runtime.h>
#include <math.h>

#define H 1024
#define V 128000
#define G3H 3072   // 3*H
#define NW2A 4000  // waves in logits kernel (1000 blocks x 4 waves), 32 rows each

// ws layout (floats):
//   [0 .. 6143]          gi (3072) then gh (3072)
//   [8192 .. 8192+7999]  per-wave (m, s) partials for LSE
#define WS_GI   0
#define WS_GH   G3H
#define WS_PART 8192

// ================= K1: gates =================
// gi = W_ih @ relu(emb[id]) + b_ih ; gh = W_hh @ h0 + b_hh
// 256 blocks x 256 threads = 1024 waves; wave w handles 6 consecutive rows.
// Waves [0,512) -> gi rows, [512,1024) -> gh rows.
__global__ __launch_bounds__(256) void gates_matvec(
    const int* __restrict__ ids, const float* __restrict__ hidden,
    const float* __restrict__ emb,
    const float* __restrict__ W_ih, const float* __restrict__ W_hh,
    const float* __restrict__ b_ih, const float* __restrict__ b_hh,
    float* __restrict__ ws) {
  const int tid  = threadIdx.x;
  const int lane = tid & 63;
  const int wid  = blockIdx.x * 4 + (tid >> 6);   // 0..1023
  const bool isGi = (wid < 512);
  const int row0 = (isGi ? wid : wid - 512) * 6;

  const float* Wm = isGi ? W_ih : W_hh;
  const float* xp = isGi ? (emb + (size_t)ids[0] * H) : hidden;

  // hoist x fragments (16 floats per lane), relu for the gi path
  float4 x0 = ((const float4*)xp)[lane];
  float4 x1 = ((const float4*)xp)[lane + 64];
  float4 x2 = ((const float4*)xp)[lane + 128];
  float4 x3 = ((const float4*)xp)[lane + 192];
  if (isGi) {
    x0.x=fmaxf(x0.x,0.f); x0.y=fmaxf(x0.y,0.f); x0.z=fmaxf(x0.z,0.f); x0.w=fmaxf(x0.w,0.f);
    x1.x=fmaxf(x1.x,0.f); x1.y=fmaxf(x1.y,0.f); x1.z=fmaxf(x1.z,0.f); x1.w=fmaxf(x1.w,0.f);
    x2.x=fmaxf(x2.x,0.f); x2.y=fmaxf(x2.y,0.f); x2.z=fmaxf(x2.z,0.f); x2.w=fmaxf(x2.w,0.f);
    x3.x=fmaxf(x3.x,0.f); x3.y=fmaxf(x3.y,0.f); x3.z=fmaxf(x3.z,0.f); x3.w=fmaxf(x3.w,0.f);
  }

#pragma unroll 2
  for (int r = 0; r < 6; ++r) {
    const int row = row0 + r;
    const float4* w = (const float4*)(Wm + (size_t)row * H);
    const float4 a = w[lane];
    const float4 b = w[lane + 64];
    const float4 c = w[lane + 128];
    const float4 d = w[lane + 192];
    float p0 = fmaf(a.x,x0.x, fmaf(a.y,x0.y, fmaf(a.z,x0.z, a.w*x0.w)));
    float p1 = fmaf(b.x,x1.x, fmaf(b.y,x1.y, fmaf(b.z,x1.z, b.w*x1.w)));
    float p2 = fmaf(c.x,x2.x, fmaf(c.y,x2.y, fmaf(c.z,x2.z, c.w*x2.w)));
    float p3 = fmaf(d.x,x3.x, fmaf(d.y,x3.y, fmaf(d.z,x3.z, d.w*x3.w)));
    float s = (p0 + p1) + (p2 + p3);
#pragma unroll
    for (int off = 1; off < 64; off <<= 1) s += __shfl_xor(s, off);
    if (lane == 0) {
      if (isGi) ws[WS_GI + row] = s + b_ih[row];
      else      ws[WS_GH + row] = s + b_hh[row];
    }
  }
}

// ================= K2a: logits + per-wave LSE partials =================
// 1000 blocks x 256 threads. Each block first recomputes h1 redundantly from
// gi/gh (kernel boundary guarantees visibility), block 0 writes h1 to
// d_out[V..V+H). Then each wave streams 32 consecutive W_out rows, writes
// unnormalized logits to d_out[0..V), tracks online (max, sumexp) -> ws.
__global__ __launch_bounds__(256) void logits_lse(
    const float* __restrict__ hidden, const float* __restrict__ ws_in,
    const float* __restrict__ W_out, const float* __restrict__ b_out,
    float* __restrict__ d_out, float* __restrict__ ws_part) {
  __shared__ float h1s[H];
  const int tid = threadIdx.x;

  // redundant h1 recompute (4 elems/thread, coalesced)
  for (int i = tid; i < H; i += 256) {
    const float r = 1.f / (1.f + expf(-(ws_in[WS_GI + i]       + ws_in[WS_GH + i])));
    const float z = 1.f / (1.f + expf(-(ws_in[WS_GI + H + i]   + ws_in[WS_GH + H + i])));
    const float n = tanhf(ws_in[WS_GI + 2*H + i] + r * ws_in[WS_GH + 2*H + i]);
    h1s[i] = (1.f - z) * n + z * hidden[i];
  }
  __syncthreads();
  if (blockIdx.x == 0) {
    for (int i = tid; i < H; i += 256) d_out[V + i] = h1s[i];
  }

  const int lane = tid & 63;
  const int wid  = blockIdx.x * 4 + (tid >> 6);   // 0..3999
  const int row0 = wid * 32;

  // hoist h1 fragments to registers — no LDS reads in the hot loop
  const float4 x0 = ((const float4*)h1s)[lane];
  const float4 x1 = ((const float4*)h1s)[lane + 64];
  const float4 x2 = ((const float4*)h1s)[lane + 128];
  const float4 x3 = ((const float4*)h1s)[lane + 192];

  float m = -INFINITY, S = 0.f;
#pragma unroll 2
  for (int r = 0; r < 32; ++r) {
    const int row = row0 + r;
    const float4* w = (const float4*)(W_out + (size_t)row * H);
    const float4 a = w[lane];
    const float4 b = w[lane + 64];
    const float4 c = w[lane + 128];
    const float4 d = w[lane + 192];
    float p0 = fmaf(a.x,x0.x, fmaf(a.y,x0.y, fmaf(a.z,x0.z, a.w*x0.w)));
    float p1 = fmaf(b.x,x1.x, fmaf(b.y,x1.y, fmaf(b.z,x1.z, b.w*x1.w)));
    float p2 = fmaf(c.x,x2.x, fmaf(c.y,x2.y, fmaf(c.z,x2.z, c.w*x2.w)));
    float p3 = fmaf(d.x,x3.x, fmaf(d.y,x3.y, fmaf(d.z,x3.z, d.w*x3.w)));
    float s = (p0 + p1) + (p2 + p3);
#pragma unroll
    for (int off = 1; off < 64; off <<= 1) s += __shfl_xor(s, off);
    const float logit = s + b_out[row];   // all lanes hold it (xor butterfly)
    if (lane == 0) d_out[row] = logit;
    const float mn = fmaxf(m, logit);
    S = S * expf(m - mn) + expf(logit - mn);
    m = mn;
  }
  if (lane == 0) {
    ws_part[2 * wid]     = m;
    ws_part[2 * wid + 1] = S;
  }
}

// ================= K2b: combine partials + normalize in place =================
// 500 blocks x 256 threads; every block redundantly folds the 4000 (m,s)
// pairs (32 KB, L2-resident), then normalizes its own 256 logits.
__global__ __launch_bounds__(256) void lse_norm(
    float* __restrict__ d_out, const float* __restrict__ ws_part) {
  __shared__ float redm[256], reds[256];
  const int tid = threadIdx.x;

  float m = -INFINITY, S = 0.f;
  for (int b = tid; b < NW2A; b += 256) {
    const float mb = ws_part[2*b], sb = ws_part[2*b+1];
    const float mn = fmaxf(m, mb);
    S = S * expf(m - mn) + sb * expf(mb - mn);
    m = mn;
  }
  redm[tid] = m; reds[tid] = S;
  __syncthreads();
  for (int s = 128; s > 0; s >>= 1) {
    if (tid < s) {
      const float m2 = redm[tid + s], s2 = reds[tid + s];
      const float mn = fmaxf(redm[tid], m2);
      reds[tid] = reds[tid] * expf(redm[tid] - mn) + s2 * expf(m2 - mn);
      redm[tid] = mn;
    }
    __syncthreads();
  }
  const float lse = redm[0] + logf(reds[0]);

  const int i = blockIdx.x * 256 + tid;   // 500*256 == V exactly
  d_out[i] -= lse;
}

extern "C" void kernel_launch(void* const* d_in, const int* in_sizes, int n_in,
                              void* d_out, int out_size, void* d_ws, size_t ws_size,
                              hipStream_t stream) {
  const int*   ids    = (const int*)d_in[0];
  const float* hidden = (const float*)d_in[1];
  const float* emb    = (const float*)d_in[2];
  const float* W_ih   = (const float*)d_in[3];
  const float* W_hh   = (const float*)d_in[4];
  const float* b_ih   = (const float*)d_in[5];
  const float* b_hh   = (const float*)d_in[6];
  const float* W_out  = (const float*)d_in[7];
  const float* b_out  = (const float*)d_in[8];
  float* out = (float*)d_out;
  float* ws  = (float*)d_ws;

  gates_matvec<<<256, 256, 0, stream>>>(ids, hidden, emb, W_ih, W_hh, b_ih, b_hh, ws);
  logits_lse<<<1000, 256, 0, stream>>>(hidden, ws, W_out, b_out, out, ws + WS_PART);
  lse_norm<<<500, 256, 0, stream>>>(out, ws + WS_PART);
}

// Round 3
// 127.872 us; speedup vs baseline: 1.0491x; 1.0491x over previous
//
#include <hip/hip_runtime.h>
#include <math.h>

#define H 1024
#define V 128000
#define G3H 3072    // 3*H
#define NWL 16000   // waves in logits kernel (4000 blocks x 4 waves), 8 rows each

// ws layout (floats):
//   [0 .. 6143]            gi (3072) then gh (3072)
//   [8192 .. 8192+31999]   per-wave (m, S) partials for LSE
#define WS_GI   0
#define WS_GH   G3H
#define WS_PART 8192

// dot of one float4 quad against x quad
#define DOT4(w_, x_) fmaf((w_).x,(x_).x, fmaf((w_).y,(x_).y, fmaf((w_).z,(x_).z, (w_).w*(x_).w)))

// ================= K1: gates =================
// gi = W_ih @ relu(emb[id]) + b_ih ; gh = W_hh @ h0 + b_hh
// 768 blocks x 256 threads = 3072 waves; each wave handles 2 consecutive rows.
// Waves [0,1536) -> gi rows, [1536,3072) -> gh rows.
__global__ __launch_bounds__(256) void gates_matvec(
    const int* __restrict__ ids, const float* __restrict__ hidden,
    const float* __restrict__ emb,
    const float* __restrict__ W_ih, const float* __restrict__ W_hh,
    const float* __restrict__ b_ih, const float* __restrict__ b_hh,
    float* __restrict__ ws) {
  const int tid  = threadIdx.x;
  const int lane = tid & 63;
  const int wid  = blockIdx.x * 4 + (tid >> 6);   // 0..3071
  const bool isGi = (wid < 1536);
  const int row0 = (isGi ? wid : wid - 1536) * 2;

  const float* Wm = isGi ? W_ih : W_hh;
  const float* xp = isGi ? (emb + (size_t)ids[0] * H) : hidden;

  float4 x0 = ((const float4*)xp)[lane];
  float4 x1 = ((const float4*)xp)[lane + 64];
  float4 x2 = ((const float4*)xp)[lane + 128];
  float4 x3 = ((const float4*)xp)[lane + 192];
  if (isGi) {
    x0.x=fmaxf(x0.x,0.f); x0.y=fmaxf(x0.y,0.f); x0.z=fmaxf(x0.z,0.f); x0.w=fmaxf(x0.w,0.f);
    x1.x=fmaxf(x1.x,0.f); x1.y=fmaxf(x1.y,0.f); x1.z=fmaxf(x1.z,0.f); x1.w=fmaxf(x1.w,0.f);
    x2.x=fmaxf(x2.x,0.f); x2.y=fmaxf(x2.y,0.f); x2.z=fmaxf(x2.z,0.f); x2.w=fmaxf(x2.w,0.f);
    x3.x=fmaxf(x3.x,0.f); x3.y=fmaxf(x3.y,0.f); x3.z=fmaxf(x3.z,0.f); x3.w=fmaxf(x3.w,0.f);
  }

  const float4* wa = (const float4*)(Wm + (size_t)row0 * H);
  const float4* wb = (const float4*)(Wm + (size_t)(row0 + 1) * H);
  const float4 a0 = wa[lane], a1 = wa[lane+64], a2 = wa[lane+128], a3 = wa[lane+192];
  const float4 b0 = wb[lane], b1 = wb[lane+64], b2 = wb[lane+128], b3 = wb[lane+192];
  float pa = (DOT4(a0,x0) + DOT4(a1,x1)) + (DOT4(a2,x2) + DOT4(a3,x3));
  float pb = (DOT4(b0,x0) + DOT4(b1,x1)) + (DOT4(b2,x2) + DOT4(b3,x3));
#pragma unroll
  for (int off = 1; off < 64; off <<= 1) {
    pa += __shfl_xor(pa, off);
    pb += __shfl_xor(pb, off);
  }
  if (lane < 2) {
    const int row = row0 + lane;
    const float s = (lane == 0) ? pa : pb;
    if (isGi) ws[WS_GI + row] = s + b_ih[row];
    else      ws[WS_GH + row] = s + b_hh[row];
  }
}

// ================= K2: logits + per-wave LSE partials =================
// 4000 blocks x 256 threads; each block recomputes h1 from gi/gh into LDS
// (kernel boundary guarantees gi/gh visibility). Block 0 writes h1 to
// d_out[V..V+H). Each wave streams 8 consecutive W_out rows in pairs
// (8 float4 loads in flight), reduces all 8 rows once at the end.
__global__ __launch_bounds__(256) void logits_lse(
    const float* __restrict__ hidden, const float* __restrict__ ws_in,
    const float* __restrict__ W_out, const float* __restrict__ b_out,
    float* __restrict__ d_out, float* __restrict__ ws_part) {
  __shared__ __align__(16) float h1s[H];
  const int tid = threadIdx.x;

  for (int i = tid; i < H; i += 256) {
    const float r = 1.f / (1.f + expf(-(ws_in[WS_GI + i]     + ws_in[WS_GH + i])));
    const float z = 1.f / (1.f + expf(-(ws_in[WS_GI + H + i] + ws_in[WS_GH + H + i])));
    const float n = tanhf(ws_in[WS_GI + 2*H + i] + r * ws_in[WS_GH + 2*H + i]);
    h1s[i] = (1.f - z) * n + z * hidden[i];
  }
  __syncthreads();
  if (blockIdx.x == 0) {
    for (int i = tid; i < H; i += 256) d_out[V + i] = h1s[i];
  }

  const int lane = tid & 63;
  const int wid  = blockIdx.x * 4 + (tid >> 6);   // 0..15999
  const int row0 = wid * 8;

  const float4 x0 = ((const float4*)h1s)[lane];
  const float4 x1 = ((const float4*)h1s)[lane + 64];
  const float4 x2 = ((const float4*)h1s)[lane + 128];
  const float4 x3 = ((const float4*)h1s)[lane + 192];

  float p[8];
#pragma unroll
  for (int pr = 0; pr < 4; ++pr) {
    const float4* wa = (const float4*)(W_out + (size_t)(row0 + 2*pr)     * H);
    const float4* wb = (const float4*)(W_out + (size_t)(row0 + 2*pr + 1) * H);
    const float4 a0 = wa[lane], a1 = wa[lane+64], a2 = wa[lane+128], a3 = wa[lane+192];
    const float4 b0 = wb[lane], b1 = wb[lane+64], b2 = wb[lane+128], b3 = wb[lane+192];
    p[2*pr]   = (DOT4(a0,x0) + DOT4(a1,x1)) + (DOT4(a2,x2) + DOT4(a3,x3));
    p[2*pr+1] = (DOT4(b0,x0) + DOT4(b1,x1)) + (DOT4(b2,x2) + DOT4(b3,x3));
  }

  // 8 interleaved butterflies, 6-deep dependency total
#pragma unroll
  for (int off = 1; off < 64; off <<= 1) {
#pragma unroll
    for (int r = 0; r < 8; ++r) p[r] += __shfl_xor(p[r], off);
  }

  // bias (wave-uniform 32B read), logits as named scalars
  const float4 bo0 = ((const float4*)(b_out + row0))[0];
  const float4 bo1 = ((const float4*)(b_out + row0))[1];
  const float l0 = p[0] + bo0.x, l1 = p[1] + bo0.y, l2 = p[2] + bo0.z, l3 = p[3] + bo0.w;
  const float l4 = p[4] + bo1.x, l5 = p[5] + bo1.y, l6 = p[6] + bo1.z, l7 = p[7] + bo1.w;

  if (lane == 0) d_out[row0 + 0] = l0;
  if (lane == 1) d_out[row0 + 1] = l1;
  if (lane == 2) d_out[row0 + 2] = l2;
  if (lane == 3) d_out[row0 + 3] = l3;
  if (lane == 4) d_out[row0 + 4] = l4;
  if (lane == 5) d_out[row0 + 5] = l5;
  if (lane == 6) d_out[row0 + 6] = l6;
  if (lane == 7) d_out[row0 + 7] = l7;

  // per-wave LSE partial, computed once per 32 KB streamed (all lanes uniform)
  const float m = fmaxf(fmaxf(fmaxf(l0,l1), fmaxf(l2,l3)), fmaxf(fmaxf(l4,l5), fmaxf(l6,l7)));
  const float S = expf(l0-m) + expf(l1-m) + expf(l2-m) + expf(l3-m)
                + expf(l4-m) + expf(l5-m) + expf(l6-m) + expf(l7-m);
  if (lane == 0) {
    ws_part[2*wid]     = m;
    ws_part[2*wid + 1] = S;
  }
}

// ================= K3: combine partials + normalize in place =================
// 500 blocks x 256; every block redundantly folds the 16000 (m,S) pairs
// (128 KB, L2-resident), then normalizes its own 256 logits.
__global__ __launch_bounds__(256) void lse_norm(
    float* __restrict__ d_out, const float* __restrict__ ws_part) {
  __shared__ float redm[256], reds[256];
  const int tid = threadIdx.x;

  float m = -INFINITY, S = 0.f;
  for (int b = tid; b < NWL; b += 256) {
    const float mb = ws_part[2*b], sb = ws_part[2*b+1];
    const float mn = fmaxf(m, mb);
    S = S * expf(m - mn) + sb * expf(mb - mn);
    m = mn;
  }
  redm[tid] = m; reds[tid] = S;
  __syncthreads();
  for (int s = 128; s > 0; s >>= 1) {
    if (tid < s) {
      const float m2 = redm[tid + s], s2 = reds[tid + s];
      const float mn = fmaxf(redm[tid], m2);
      reds[tid] = reds[tid] * expf(redm[tid] - mn) + s2 * expf(m2 - mn);
      redm[tid] = mn;
    }
    __syncthreads();
  }
  const float lse = redm[0] + logf(reds[0]);

  const int i = blockIdx.x * 256 + tid;   // 500*256 == V exactly
  d_out[i] -= lse;
}

extern "C" void kernel_launch(void* const* d_in, const int* in_sizes, int n_in,
                              void* d_out, int out_size, void* d_ws, size_t ws_size,
                              hipStream_t stream) {
  const int*   ids    = (const int*)d_in[0];
  const float* hidden = (const float*)d_in[1];
  const float* emb    = (const float*)d_in[2];
  const float* W_ih   = (const float*)d_in[3];
  const float* W_hh   = (const float*)d_in[4];
  const float* b_ih   = (const float*)d_in[5];
  const float* b_hh   = (const float*)d_in[6];
  const float* W_out  = (const float*)d_in[7];
  const float* b_out  = (const float*)d_in[8];
  float* out = (float*)d_out;
  float* ws  = (float*)d_ws;

  gates_matvec<<<768, 256, 0, stream>>>(ids, hidden, emb, W_ih, W_hh, b_ih, b_hh, ws);
  logits_lse<<<4000, 256, 0, stream>>>(hidden, ws, W_out, b_out, out, ws + WS_PART);
  lse_norm<<<500, 256, 0, stream>>>(out, ws + WS_PART);
}

// Round 4
// 115.754 us; speedup vs baseline: 1.1589x; 1.1047x over previous
//
#include <hip/hip_runtime.h>
#include <math.h>

#define H 1024
#define V 128000
#define G3H 3072    // 3*H
#define NWL 16000   // row-groups in logits kernel (4000 blocks x 4 waves), 8 rows each

// ws layout (floats):
//   [0 .. 6143]            gi (3072) then gh (3072)
//   [8192 .. 8192+31999]   per-wave (m, S) partials for LSE
#define WS_GI   0
#define WS_GH   G3H
#define WS_PART 8192

typedef float f32x4 __attribute__((ext_vector_type(4)));

// dot of one quad against x quad
#define DOT4(w_, x_) fmaf((w_).x,(x_).x, fmaf((w_).y,(x_).y, fmaf((w_).z,(x_).z, (w_).w*(x_).w)))

// ================= K1: gates =================
// gi = W_ih @ relu(emb[id]) + b_ih ; gh = W_hh @ h0 + b_hh
// 768 blocks x 256 threads = 3072 waves; each wave handles 2 consecutive rows.
// Waves [0,1536) -> gi rows, [1536,3072) -> gh rows.
__global__ __launch_bounds__(256) void gates_matvec(
    const int* __restrict__ ids, const float* __restrict__ hidden,
    const float* __restrict__ emb,
    const float* __restrict__ W_ih, const float* __restrict__ W_hh,
    const float* __restrict__ b_ih, const float* __restrict__ b_hh,
    float* __restrict__ ws) {
  const int tid  = threadIdx.x;
  const int lane = tid & 63;
  const int wid  = blockIdx.x * 4 + (tid >> 6);   // 0..3071
  const bool isGi = (wid < 1536);
  const int row0 = (isGi ? wid : wid - 1536) * 2;

  const float* Wm = isGi ? W_ih : W_hh;
  const float* xp = isGi ? (emb + (size_t)ids[0] * H) : hidden;

  // x vector is reused by 1536 waves -> normal (caching) loads
  f32x4 x0 = ((const f32x4*)xp)[lane];
  f32x4 x1 = ((const f32x4*)xp)[lane + 64];
  f32x4 x2 = ((const f32x4*)xp)[lane + 128];
  f32x4 x3 = ((const f32x4*)xp)[lane + 192];
  if (isGi) {
    x0.x=fmaxf(x0.x,0.f); x0.y=fmaxf(x0.y,0.f); x0.z=fmaxf(x0.z,0.f); x0.w=fmaxf(x0.w,0.f);
    x1.x=fmaxf(x1.x,0.f); x1.y=fmaxf(x1.y,0.f); x1.z=fmaxf(x1.z,0.f); x1.w=fmaxf(x1.w,0.f);
    x2.x=fmaxf(x2.x,0.f); x2.y=fmaxf(x2.y,0.f); x2.z=fmaxf(x2.z,0.f); x2.w=fmaxf(x2.w,0.f);
    x3.x=fmaxf(x3.x,0.f); x3.y=fmaxf(x3.y,0.f); x3.z=fmaxf(x3.z,0.f); x3.w=fmaxf(x3.w,0.f);
  }

  // weight rows are single-use streams -> non-temporal loads
  const f32x4* wa = (const f32x4*)(Wm + (size_t)row0 * H);
  const f32x4* wb = (const f32x4*)(Wm + (size_t)(row0 + 1) * H);
  const f32x4 a0 = __builtin_nontemporal_load(wa + lane);
  const f32x4 a1 = __builtin_nontemporal_load(wa + lane + 64);
  const f32x4 a2 = __builtin_nontemporal_load(wa + lane + 128);
  const f32x4 a3 = __builtin_nontemporal_load(wa + lane + 192);
  const f32x4 b0 = __builtin_nontemporal_load(wb + lane);
  const f32x4 b1 = __builtin_nontemporal_load(wb + lane + 64);
  const f32x4 b2 = __builtin_nontemporal_load(wb + lane + 128);
  const f32x4 b3 = __builtin_nontemporal_load(wb + lane + 192);
  float pa = (DOT4(a0,x0) + DOT4(a1,x1)) + (DOT4(a2,x2) + DOT4(a3,x3));
  float pb = (DOT4(b0,x0) + DOT4(b1,x1)) + (DOT4(b2,x2) + DOT4(b3,x3));
#pragma unroll
  for (int off = 1; off < 64; off <<= 1) {
    pa += __shfl_xor(pa, off);
    pb += __shfl_xor(pb, off);
  }
  if (lane < 2) {
    const int row = row0 + lane;
    const float s = (lane == 0) ? pa : pb;
    if (isGi) ws[WS_GI + row] = s + b_ih[row];
    else      ws[WS_GH + row] = s + b_hh[row];
  }
}

// ================= K2: logits + per-wave LSE partials =================
// 4000 blocks x 256 threads; each block recomputes h1 from gi/gh into LDS
// (kernel boundary guarantees gi/gh visibility). Block 0 writes h1 to
// d_out[V..V+H). Each wave streams 8 consecutive W_out rows in pairs
// (8 nt-float4 loads in flight), reduces all 8 rows once at the end.
__global__ __launch_bounds__(256) void logits_lse(
    const float* __restrict__ hidden, const float* __restrict__ ws_in,
    const float* __restrict__ W_out, const float* __restrict__ b_out,
    float* __restrict__ d_out, float* __restrict__ ws_part) {
  __shared__ __align__(16) float h1s[H];
  const int tid = threadIdx.x;

  for (int i = tid; i < H; i += 256) {
    const float r = 1.f / (1.f + expf(-(ws_in[WS_GI + i]     + ws_in[WS_GH + i])));
    const float z = 1.f / (1.f + expf(-(ws_in[WS_GI + H + i] + ws_in[WS_GH + H + i])));
    const float n = tanhf(ws_in[WS_GI + 2*H + i] + r * ws_in[WS_GH + 2*H + i]);
    h1s[i] = (1.f - z) * n + z * hidden[i];
  }
  __syncthreads();
  if (blockIdx.x == 0) {
    for (int i = tid; i < H; i += 256) d_out[V + i] = h1s[i];
  }

  const int lane = tid & 63;
  const int wid  = blockIdx.x * 4 + (tid >> 6);   // 0..15999
  const int row0 = wid * 8;

  const f32x4 x0 = ((const f32x4*)h1s)[lane];
  const f32x4 x1 = ((const f32x4*)h1s)[lane + 64];
  const f32x4 x2 = ((const f32x4*)h1s)[lane + 128];
  const f32x4 x3 = ((const f32x4*)h1s)[lane + 192];

  float p[8];
#pragma unroll
  for (int pr = 0; pr < 4; ++pr) {
    const f32x4* wa = (const f32x4*)(W_out + (size_t)(row0 + 2*pr)     * H);
    const f32x4* wb = (const f32x4*)(W_out + (size_t)(row0 + 2*pr + 1) * H);
    const f32x4 a0 = __builtin_nontemporal_load(wa + lane);
    const f32x4 a1 = __builtin_nontemporal_load(wa + lane + 64);
    const f32x4 a2 = __builtin_nontemporal_load(wa + lane + 128);
    const f32x4 a3 = __builtin_nontemporal_load(wa + lane + 192);
    const f32x4 b0 = __builtin_nontemporal_load(wb + lane);
    const f32x4 b1 = __builtin_nontemporal_load(wb + lane + 64);
    const f32x4 b2 = __builtin_nontemporal_load(wb + lane + 128);
    const f32x4 b3 = __builtin_nontemporal_load(wb + lane + 192);
    p[2*pr]   = (DOT4(a0,x0) + DOT4(a1,x1)) + (DOT4(a2,x2) + DOT4(a3,x3));
    p[2*pr+1] = (DOT4(b0,x0) + DOT4(b1,x1)) + (DOT4(b2,x2) + DOT4(b3,x3));
  }

  // 8 interleaved butterflies, 6-deep dependency total
#pragma unroll
  for (int off = 1; off < 64; off <<= 1) {
#pragma unroll
    for (int r = 0; r < 8; ++r) p[r] += __shfl_xor(p[r], off);
  }

  // bias (wave-uniform 32B read), logits as named scalars
  const float4 bo0 = ((const float4*)(b_out + row0))[0];
  const float4 bo1 = ((const float4*)(b_out + row0))[1];
  const float l0 = p[0] + bo0.x, l1 = p[1] + bo0.y, l2 = p[2] + bo0.z, l3 = p[3] + bo0.w;
  const float l4 = p[4] + bo1.x, l5 = p[5] + bo1.y, l6 = p[6] + bo1.z, l7 = p[7] + bo1.w;

  if (lane == 0) d_out[row0 + 0] = l0;
  if (lane == 1) d_out[row0 + 1] = l1;
  if (lane == 2) d_out[row0 + 2] = l2;
  if (lane == 3) d_out[row0 + 3] = l3;
  if (lane == 4) d_out[row0 + 4] = l4;
  if (lane == 5) d_out[row0 + 5] = l5;
  if (lane == 6) d_out[row0 + 6] = l6;
  if (lane == 7) d_out[row0 + 7] = l7;

  // per-wave LSE partial, computed once per 32 KB streamed (all lanes uniform)
  const float m = fmaxf(fmaxf(fmaxf(l0,l1), fmaxf(l2,l3)), fmaxf(fmaxf(l4,l5), fmaxf(l6,l7)));
  const float S = expf(l0-m) + expf(l1-m) + expf(l2-m) + expf(l3-m)
                + expf(l4-m) + expf(l5-m) + expf(l6-m) + expf(l7-m);
  if (lane == 0) {
    ws_part[2*wid]     = m;
    ws_part[2*wid + 1] = S;
  }
}

// ================= K3: combine partials + normalize in place =================
// 500 blocks x 256; every block redundantly folds the 16000 (m,S) pairs
// (128 KB, L2-resident), then normalizes its own 256 logits.
__global__ __launch_bounds__(256) void lse_norm(
    float* __restrict__ d_out, const float* __restrict__ ws_part) {
  __shared__ float redm[256], reds[256];
  const int tid = threadIdx.x;

  float m = -INFINITY, S = 0.f;
  for (int b = tid; b < NWL; b += 256) {
    const float mb = ws_part[2*b], sb = ws_part[2*b+1];
    const float mn = fmaxf(m, mb);
    S = S * expf(m - mn) + sb * expf(mb - mn);
    m = mn;
  }
  redm[tid] = m; reds[tid] = S;
  __syncthreads();
  for (int s = 128; s > 0; s >>= 1) {
    if (tid < s) {
      const float m2 = redm[tid + s], s2 = reds[tid + s];
      const float mn = fmaxf(redm[tid], m2);
      reds[tid] = reds[tid] * expf(redm[tid] - mn) + s2 * expf(m2 - mn);
      redm[tid] = mn;
    }
    __syncthreads();
  }
  const float lse = redm[0] + logf(reds[0]);

  const int i = blockIdx.x * 256 + tid;   // 500*256 == V exactly
  d_out[i] -= lse;
}

extern "C" void kernel_launch(void* const* d_in, const int* in_sizes, int n_in,
                              void* d_out, int out_size, void* d_ws, size_t ws_size,
                              hipStream_t stream) {
  const int*   ids    = (const int*)d_in[0];
  const float* hidden = (const float*)d_in[1];
  const float* emb    = (const float*)d_in[2];
  const float* W_ih   = (const float*)d_in[3];
  const float* W_hh   = (const float*)d_in[4];
  const float* b_ih   = (const float*)d_in[5];
  const float* b_hh   = (const float*)d_in[6];
  const float* W_out  = (const float*)d_in[7];
  const float* b_out  = (const float*)d_in[8];
  float* out = (float*)d_out;
  float* ws  = (float*)d_ws;

  gates_matvec<<<768, 256, 0, stream>>>(ids, hidden, emb, W_ih, W_hh, b_ih, b_hh, ws);
  logits_lse<<<4000, 256, 0, stream>>>(hidden, ws, W_out, b_out, out, ws + WS_PART);
  lse_norm<<<500, 256, 0, stream>>>(out, ws + WS_PART);
}

// Round 5
// 102.749 us; speedup vs baseline: 1.3056x; 1.1266x over previous
//
#include <hip/hip_runtime.h>
#include <math.h>

#define H 1024
#define V 128000
#define G3H 3072     // 3*H

#define K2_BLOCKS 1024
#define K2_WAVES  (K2_BLOCKS * 4)   // 4096 waves, all co-resident
#define K2_GROUPS (V / 4)           // 32000 groups of 4 rows

// ws layout (floats):
//   [0 .. 6143]           gi (3072) then gh (3072)
//   [8192 .. 8192+8191]   per-wave (m, S) partials for LSE
#define WS_GI   0
#define WS_GH   G3H
#define WS_PART 8192

typedef float f32x4 __attribute__((ext_vector_type(4)));

#define DOT4(w_, x_) fmaf((w_).x,(x_).x, fmaf((w_).y,(x_).y, fmaf((w_).z,(x_).z, (w_).w*(x_).w)))

// ================= K1: gates =================
// gi = W_ih @ relu(emb[id]) + b_ih ; gh = W_hh @ h0 + b_hh
// 768 blocks x 256 threads = 3072 waves; each wave handles 2 consecutive rows.
__global__ __launch_bounds__(256) void gates_matvec(
    const int* __restrict__ ids, const float* __restrict__ hidden,
    const float* __restrict__ emb,
    const float* __restrict__ W_ih, const float* __restrict__ W_hh,
    const float* __restrict__ b_ih, const float* __restrict__ b_hh,
    float* __restrict__ ws) {
  const int tid  = threadIdx.x;
  const int lane = tid & 63;
  const int wid  = blockIdx.x * 4 + (tid >> 6);   // 0..3071
  const bool isGi = (wid < 1536);
  const int row0 = (isGi ? wid : wid - 1536) * 2;

  const float* Wm = isGi ? W_ih : W_hh;
  const float* xp = isGi ? (emb + (size_t)ids[0] * H) : hidden;

  f32x4 x0 = ((const f32x4*)xp)[lane];
  f32x4 x1 = ((const f32x4*)xp)[lane + 64];
  f32x4 x2 = ((const f32x4*)xp)[lane + 128];
  f32x4 x3 = ((const f32x4*)xp)[lane + 192];
  if (isGi) {
    x0.x=fmaxf(x0.x,0.f); x0.y=fmaxf(x0.y,0.f); x0.z=fmaxf(x0.z,0.f); x0.w=fmaxf(x0.w,0.f);
    x1.x=fmaxf(x1.x,0.f); x1.y=fmaxf(x1.y,0.f); x1.z=fmaxf(x1.z,0.f); x1.w=fmaxf(x1.w,0.f);
    x2.x=fmaxf(x2.x,0.f); x2.y=fmaxf(x2.y,0.f); x2.z=fmaxf(x2.z,0.f); x2.w=fmaxf(x2.w,0.f);
    x3.x=fmaxf(x3.x,0.f); x3.y=fmaxf(x3.y,0.f); x3.z=fmaxf(x3.z,0.f); x3.w=fmaxf(x3.w,0.f);
  }

  const f32x4* wa = (const f32x4*)(Wm + (size_t)row0 * H);
  const f32x4* wb = (const f32x4*)(Wm + (size_t)(row0 + 1) * H);
  const f32x4 a0 = __builtin_nontemporal_load(wa + lane);
  const f32x4 a1 = __builtin_nontemporal_load(wa + lane + 64);
  const f32x4 a2 = __builtin_nontemporal_load(wa + lane + 128);
  const f32x4 a3 = __builtin_nontemporal_load(wa + lane + 192);
  const f32x4 b0 = __builtin_nontemporal_load(wb + lane);
  const f32x4 b1 = __builtin_nontemporal_load(wb + lane + 64);
  const f32x4 b2 = __builtin_nontemporal_load(wb + lane + 128);
  const f32x4 b3 = __builtin_nontemporal_load(wb + lane + 192);
  float pa = (DOT4(a0,x0) + DOT4(a1,x1)) + (DOT4(a2,x2) + DOT4(a3,x3));
  float pb = (DOT4(b0,x0) + DOT4(b1,x1)) + (DOT4(b2,x2) + DOT4(b3,x3));
#pragma unroll
  for (int off = 1; off < 64; off <<= 1) {
    pa += __shfl_xor(pa, off);
    pb += __shfl_xor(pb, off);
  }
  if (lane < 2) {
    const int row = row0 + lane;
    const float s = (lane == 0) ? pa : pb;
    if (isGi) ws[WS_GI + row] = s + b_ih[row];
    else      ws[WS_GH + row] = s + b_hh[row];
  }
}

// ================= K2: persistent logits + per-wave LSE partials =================
// 1024 blocks x 256 threads, all co-resident (VGPR capped via launch_bounds).
// Each block recomputes h1 from gi/gh once; block 0 writes h1 to d_out[V..).
// Each wave grid-strides over 4-row groups: 16 nt loads in flight per iter,
// one interleaved butterfly per iter, online (m,S) merged across iters.
__global__ __launch_bounds__(256, 4) void logits_lse(
    const float* __restrict__ hidden, const float* __restrict__ ws_in,
    const float* __restrict__ W_out, const float* __restrict__ b_out,
    float* __restrict__ d_out, float* __restrict__ ws_part) {
  __shared__ __align__(16) float h1s[H];
  const int tid = threadIdx.x;

  for (int i = tid; i < H; i += 256) {
    const float r = 1.f / (1.f + expf(-(ws_in[WS_GI + i]     + ws_in[WS_GH + i])));
    const float z = 1.f / (1.f + expf(-(ws_in[WS_GI + H + i] + ws_in[WS_GH + H + i])));
    const float n = tanhf(ws_in[WS_GI + 2*H + i] + r * ws_in[WS_GH + 2*H + i]);
    h1s[i] = (1.f - z) * n + z * hidden[i];
  }
  __syncthreads();
  if (blockIdx.x == 0) {
    for (int i = tid; i < H; i += 256) d_out[V + i] = h1s[i];
  }

  const int lane = tid & 63;
  const int wid  = blockIdx.x * 4 + (tid >> 6);   // 0..4095

  const f32x4 x0 = ((const f32x4*)h1s)[lane];
  const f32x4 x1 = ((const f32x4*)h1s)[lane + 64];
  const f32x4 x2 = ((const f32x4*)h1s)[lane + 128];
  const f32x4 x3 = ((const f32x4*)h1s)[lane + 192];

  float m = -INFINITY, S = 0.f;

#pragma unroll 1
  for (int g = wid; g < K2_GROUPS; g += K2_WAVES) {
    const int row0 = g * 4;
    const f32x4* w = (const f32x4*)(W_out + (size_t)row0 * H);  // 4 rows x 256 quads

    const f32x4 a0 = __builtin_nontemporal_load(w + lane);
    const f32x4 a1 = __builtin_nontemporal_load(w + lane + 64);
    const f32x4 a2 = __builtin_nontemporal_load(w + lane + 128);
    const f32x4 a3 = __builtin_nontemporal_load(w + lane + 192);
    const f32x4 b0 = __builtin_nontemporal_load(w + lane + 256);
    const f32x4 b1 = __builtin_nontemporal_load(w + lane + 320);
    const f32x4 b2 = __builtin_nontemporal_load(w + lane + 384);
    const f32x4 b3 = __builtin_nontemporal_load(w + lane + 448);
    const f32x4 c0 = __builtin_nontemporal_load(w + lane + 512);
    const f32x4 c1 = __builtin_nontemporal_load(w + lane + 576);
    const f32x4 c2 = __builtin_nontemporal_load(w + lane + 640);
    const f32x4 c3 = __builtin_nontemporal_load(w + lane + 704);
    const f32x4 d0 = __builtin_nontemporal_load(w + lane + 768);
    const f32x4 d1 = __builtin_nontemporal_load(w + lane + 832);
    const f32x4 d2 = __builtin_nontemporal_load(w + lane + 896);
    const f32x4 d3 = __builtin_nontemporal_load(w + lane + 960);

    float p0 = (DOT4(a0,x0) + DOT4(a1,x1)) + (DOT4(a2,x2) + DOT4(a3,x3));
    float p1 = (DOT4(b0,x0) + DOT4(b1,x1)) + (DOT4(b2,x2) + DOT4(b3,x3));
    float p2 = (DOT4(c0,x0) + DOT4(c1,x1)) + (DOT4(c2,x2) + DOT4(c3,x3));
    float p3 = (DOT4(d0,x0) + DOT4(d1,x1)) + (DOT4(d2,x2) + DOT4(d3,x3));

#pragma unroll
    for (int off = 1; off < 64; off <<= 1) {
      p0 += __shfl_xor(p0, off);
      p1 += __shfl_xor(p1, off);
      p2 += __shfl_xor(p2, off);
      p3 += __shfl_xor(p3, off);
    }

    const float4 bo = *(const float4*)(b_out + row0);
    const float l0 = p0 + bo.x, l1 = p1 + bo.y, l2 = p2 + bo.z, l3 = p3 + bo.w;

    const float sel = (lane == 0) ? l0 : (lane == 1) ? l1 : (lane == 2) ? l2 : l3;
    if (lane < 4) d_out[row0 + lane] = sel;

    const float m4 = fmaxf(fmaxf(l0, l1), fmaxf(l2, l3));
    const float mn = fmaxf(m, m4);
    S = S * expf(m - mn)
      + expf(l0 - mn) + expf(l1 - mn) + expf(l2 - mn) + expf(l3 - mn);
    m = mn;
  }

  if (lane == 0) {
    ws_part[2*wid]     = m;
    ws_part[2*wid + 1] = S;
  }
}

// ================= K3: combine partials + normalize in place =================
// 500 blocks x 256; every block redundantly folds the 4096 (m,S) pairs
// (32 KB, L2-resident), then normalizes its own 256 logits.
__global__ __launch_bounds__(256) void lse_norm(
    float* __restrict__ d_out, const float* __restrict__ ws_part) {
  __shared__ float redm[256], reds[256];
  const int tid = threadIdx.x;

  float m = -INFINITY, S = 0.f;
  for (int b = tid; b < K2_WAVES; b += 256) {
    const float mb = ws_part[2*b], sb = ws_part[2*b+1];
    const float mn = fmaxf(m, mb);
    S = S * expf(m - mn) + sb * expf(mb - mn);
    m = mn;
  }
  redm[tid] = m; reds[tid] = S;
  __syncthreads();
  for (int s = 128; s > 0; s >>= 1) {
    if (tid < s) {
      const float m2 = redm[tid + s], s2 = reds[tid + s];
      const float mn = fmaxf(redm[tid], m2);
      reds[tid] = reds[tid] * expf(redm[tid] - mn) + s2 * expf(m2 - mn);
      redm[tid] = mn;
    }
    __syncthreads();
  }
  const float lse = redm[0] + logf(reds[0]);

  const int i = blockIdx.x * 256 + tid;   // 500*256 == V exactly
  d_out[i] -= lse;
}

extern "C" void kernel_launch(void* const* d_in, const int* in_sizes, int n_in,
                              void* d_out, int out_size, void* d_ws, size_t ws_size,
                              hipStream_t stream) {
  const int*   ids    = (const int*)d_in[0];
  const float* hidden = (const float*)d_in[1];
  const float* emb    = (const float*)d_in[2];
  const float* W_ih   = (const float*)d_in[3];
  const float* W_hh   = (const float*)d_in[4];
  const float* b_ih   = (const float*)d_in[5];
  const float* b_hh   = (const float*)d_in[6];
  const float* W_out  = (const float*)d_in[7];
  const float* b_out  = (const float*)d_in[8];
  float* out = (float*)d_out;
  float* ws  = (float*)d_ws;

  gates_matvec<<<768, 256, 0, stream>>>(ids, hidden, emb, W_ih, W_hh, b_ih, b_hh, ws);
  logits_lse<<<K2_BLOCKS, 256, 0, stream>>>(hidden, ws, W_out, b_out, out, ws + WS_PART);
  lse_norm<<<500, 256, 0, stream>>>(out, ws + WS_PART);
}

// Round 6
// 96.970 us; speedup vs baseline: 1.3834x; 1.0596x over previous
//
#include <hip/hip_runtime.h>
#include <math.h>

#define H 1024
#define V 128000
#define G3H 3072     // 3*H

#define K2_BLOCKS 1024
#define K2_WAVES  (K2_BLOCKS * 4)   // 4096 waves, all co-resident
#define K2_GROUPS (V / 4)           // 32000 groups of 4 rows
#define NPART     K2_BLOCKS         // one (m,S) pair per block

// ws layout (floats):
//   [0 .. 6143]           gi (3072) then gh (3072)
//   [8192 .. 8192+2047]   per-block (m, S) partials for LSE
#define WS_GI   0
#define WS_GH   G3H
#define WS_PART 8192

typedef float f32x4 __attribute__((ext_vector_type(4)));

#define DOT4(w_, x_) fmaf((w_).x,(x_).x, fmaf((w_).y,(x_).y, fmaf((w_).z,(x_).z, (w_).w*(x_).w)))

__device__ __forceinline__ float sigmoid_fast(float x) {
  return 1.f / (1.f + __expf(-x));
}
__device__ __forceinline__ float tanh_fast(float x) {
  // tanh(x) = 1 - 2/(e^{2x}+1); overflow-safe (inf -> 1, 0 -> -1)
  return 1.f - 2.f / (__expf(2.f * x) + 1.f);
}

// ================= K1: gates =================
// gi = W_ih @ relu(emb[id]) + b_ih ; gh = W_hh @ h0 + b_hh
// 768 blocks x 256 threads = 3072 waves; each wave handles 2 consecutive rows.
__global__ __launch_bounds__(256) void gates_matvec(
    const int* __restrict__ ids, const float* __restrict__ hidden,
    const float* __restrict__ emb,
    const float* __restrict__ W_ih, const float* __restrict__ W_hh,
    const float* __restrict__ b_ih, const float* __restrict__ b_hh,
    float* __restrict__ ws) {
  const int tid  = threadIdx.x;
  const int lane = tid & 63;
  const int wid  = blockIdx.x * 4 + (tid >> 6);   // 0..3071
  const bool isGi = (wid < 1536);
  const int row0 = (isGi ? wid : wid - 1536) * 2;

  const float* Wm = isGi ? W_ih : W_hh;
  const float* xp = isGi ? (emb + (size_t)ids[0] * H) : hidden;

  f32x4 x0 = ((const f32x4*)xp)[lane];
  f32x4 x1 = ((const f32x4*)xp)[lane + 64];
  f32x4 x2 = ((const f32x4*)xp)[lane + 128];
  f32x4 x3 = ((const f32x4*)xp)[lane + 192];
  if (isGi) {
    x0.x=fmaxf(x0.x,0.f); x0.y=fmaxf(x0.y,0.f); x0.z=fmaxf(x0.z,0.f); x0.w=fmaxf(x0.w,0.f);
    x1.x=fmaxf(x1.x,0.f); x1.y=fmaxf(x1.y,0.f); x1.z=fmaxf(x1.z,0.f); x1.w=fmaxf(x1.w,0.f);
    x2.x=fmaxf(x2.x,0.f); x2.y=fmaxf(x2.y,0.f); x2.z=fmaxf(x2.z,0.f); x2.w=fmaxf(x2.w,0.f);
    x3.x=fmaxf(x3.x,0.f); x3.y=fmaxf(x3.y,0.f); x3.z=fmaxf(x3.z,0.f); x3.w=fmaxf(x3.w,0.f);
  }

  const f32x4* wa = (const f32x4*)(Wm + (size_t)row0 * H);
  const f32x4* wb = (const f32x4*)(Wm + (size_t)(row0 + 1) * H);
  const f32x4 a0 = __builtin_nontemporal_load(wa + lane);
  const f32x4 a1 = __builtin_nontemporal_load(wa + lane + 64);
  const f32x4 a2 = __builtin_nontemporal_load(wa + lane + 128);
  const f32x4 a3 = __builtin_nontemporal_load(wa + lane + 192);
  const f32x4 b0 = __builtin_nontemporal_load(wb + lane);
  const f32x4 b1 = __builtin_nontemporal_load(wb + lane + 64);
  const f32x4 b2 = __builtin_nontemporal_load(wb + lane + 128);
  const f32x4 b3 = __builtin_nontemporal_load(wb + lane + 192);
  float pa = (DOT4(a0,x0) + DOT4(a1,x1)) + (DOT4(a2,x2) + DOT4(a3,x3));
  float pb = (DOT4(b0,x0) + DOT4(b1,x1)) + (DOT4(b2,x2) + DOT4(b3,x3));
#pragma unroll
  for (int off = 1; off < 64; off <<= 1) {
    pa += __shfl_xor(pa, off);
    pb += __shfl_xor(pb, off);
  }
  if (lane < 2) {
    const int row = row0 + lane;
    const float s = (lane == 0) ? pa : pb;
    if (isGi) ws[WS_GI + row] = s + b_ih[row];
    else      ws[WS_GH + row] = s + b_hh[row];
  }
}

// ================= K2: persistent logits + per-block LSE partials =================
// 1024 blocks x 256 threads, all co-resident. Balanced contiguous ranges:
// wave w owns groups [w*32000>>12, (w+1)*32000>>12) -> 7 or 8 each.
__global__ __launch_bounds__(256, 4) void logits_lse(
    const float* __restrict__ hidden, const float* __restrict__ ws_in,
    const float* __restrict__ W_out, const float* __restrict__ b_out,
    float* __restrict__ d_out, float* __restrict__ ws_part) {
  __shared__ __align__(16) f32x4 h1s4[256];
  __shared__ float wpm[4], wps[4];
  const int tid = threadIdx.x;

  // --- h1 recompute: 1 quad/thread, fast transcendentals ---
  {
    const f32x4* ws4 = (const f32x4*)ws_in;
    const f32x4 gi0 = ws4[tid];          // gi[0:H]
    const f32x4 gi1 = ws4[tid + 256];    // gi[H:2H]
    const f32x4 gi2 = ws4[tid + 512];    // gi[2H:3H]
    const f32x4 gh0 = ws4[tid + 768];    // gh[0:H]
    const f32x4 gh1 = ws4[tid + 1024];   // gh[H:2H]
    const f32x4 gh2 = ws4[tid + 1280];   // gh[2H:3H]
    const f32x4 h0v = ((const f32x4*)hidden)[tid];
    f32x4 h1;
#pragma unroll
    for (int j = 0; j < 4; ++j) {
      const float r = sigmoid_fast(gi0[j] + gh0[j]);
      const float z = sigmoid_fast(gi1[j] + gh1[j]);
      const float n = tanh_fast(gi2[j] + r * gh2[j]);
      h1[j] = (1.f - z) * n + z * h0v[j];
    }
    h1s4[tid] = h1;
  }
  __syncthreads();
  if (blockIdx.x == 0) {
    ((f32x4*)(d_out + V))[tid] = h1s4[tid];
  }

  const int lane = tid & 63;
  const int wid  = blockIdx.x * 4 + (tid >> 6);   // 0..4095
  const int gbeg = (wid * K2_GROUPS) >> 12;       // /4096
  const int gend = ((wid + 1) * K2_GROUPS) >> 12;

  const f32x4 x0 = h1s4[lane];
  const f32x4 x1 = h1s4[lane + 64];
  const f32x4 x2 = h1s4[lane + 128];
  const f32x4 x3 = h1s4[lane + 192];

  float m = -INFINITY, S = 0.f;

#pragma unroll 1
  for (int g = gbeg; g < gend; ++g) {
    const int row0 = g * 4;
    const f32x4* w = (const f32x4*)(W_out + (size_t)row0 * H);  // 4 rows x 256 quads

    const f32x4 a0 = __builtin_nontemporal_load(w + lane);
    const f32x4 a1 = __builtin_nontemporal_load(w + lane + 64);
    const f32x4 a2 = __builtin_nontemporal_load(w + lane + 128);
    const f32x4 a3 = __builtin_nontemporal_load(w + lane + 192);
    const f32x4 b0 = __builtin_nontemporal_load(w + lane + 256);
    const f32x4 b1 = __builtin_nontemporal_load(w + lane + 320);
    const f32x4 b2 = __builtin_nontemporal_load(w + lane + 384);
    const f32x4 b3 = __builtin_nontemporal_load(w + lane + 448);
    const f32x4 c0 = __builtin_nontemporal_load(w + lane + 512);
    const f32x4 c1 = __builtin_nontemporal_load(w + lane + 576);
    const f32x4 c2 = __builtin_nontemporal_load(w + lane + 640);
    const f32x4 c3 = __builtin_nontemporal_load(w + lane + 704);
    const f32x4 d0 = __builtin_nontemporal_load(w + lane + 768);
    const f32x4 d1 = __builtin_nontemporal_load(w + lane + 832);
    const f32x4 d2 = __builtin_nontemporal_load(w + lane + 896);
    const f32x4 d3 = __builtin_nontemporal_load(w + lane + 960);

    float p0 = (DOT4(a0,x0) + DOT4(a1,x1)) + (DOT4(a2,x2) + DOT4(a3,x3));
    float p1 = (DOT4(b0,x0) + DOT4(b1,x1)) + (DOT4(b2,x2) + DOT4(b3,x3));
    float p2 = (DOT4(c0,x0) + DOT4(c1,x1)) + (DOT4(c2,x2) + DOT4(c3,x3));
    float p3 = (DOT4(d0,x0) + DOT4(d1,x1)) + (DOT4(d2,x2) + DOT4(d3,x3));

#pragma unroll
    for (int off = 1; off < 64; off <<= 1) {
      p0 += __shfl_xor(p0, off);
      p1 += __shfl_xor(p1, off);
      p2 += __shfl_xor(p2, off);
      p3 += __shfl_xor(p3, off);
    }

    const float4 bo = *(const float4*)(b_out + row0);
    const float l0 = p0 + bo.x, l1 = p1 + bo.y, l2 = p2 + bo.z, l3 = p3 + bo.w;

    const float sel = (lane == 0) ? l0 : (lane == 1) ? l1 : (lane == 2) ? l2 : l3;
    if (lane < 4) d_out[row0 + lane] = sel;

    const float m4 = fmaxf(fmaxf(l0, l1), fmaxf(l2, l3));
    const float mn = fmaxf(m, m4);
    S = S * __expf(m - mn)
      + __expf(l0 - mn) + __expf(l1 - mn) + __expf(l2 - mn) + __expf(l3 - mn);
    m = mn;
  }

  // combine the block's 4 wave partials through LDS -> 1 pair per block
  if (lane == 0) { wpm[tid >> 6] = m; wps[tid >> 6] = S; }
  __syncthreads();
  if (tid == 0) {
    float bm = wpm[0], bS = wps[0];
#pragma unroll
    for (int k = 1; k < 4; ++k) {
      const float mk = wpm[k], sk = wps[k];
      const float mn = fmaxf(bm, mk);
      bS = bS * __expf(bm - mn) + sk * __expf(mk - mn);
      bm = mn;
    }
    ws_part[2 * blockIdx.x]     = bm;
    ws_part[2 * blockIdx.x + 1] = bS;
  }
}

// ================= K3: combine partials + normalize in place =================
// 500 blocks x 256; every block redundantly folds the 1024 (m,S) pairs
// (8 KB, L2-resident), then normalizes its own 256 logits.
__global__ __launch_bounds__(256) void lse_norm(
    float* __restrict__ d_out, const float* __restrict__ ws_part) {
  __shared__ float redm[256], reds[256];
  const int tid = threadIdx.x;

  float m = -INFINITY, S = 0.f;
  for (int b = tid; b < NPART; b += 256) {   // 4 iterations
    const float mb = ws_part[2*b], sb = ws_part[2*b+1];
    const float mn = fmaxf(m, mb);
    S = S * __expf(m - mn) + sb * __expf(mb - mn);
    m = mn;
  }
  redm[tid] = m; reds[tid] = S;
  __syncthreads();
  for (int s = 128; s > 0; s >>= 1) {
    if (tid < s) {
      const float m2 = redm[tid + s], s2 = reds[tid + s];
      const float mn = fmaxf(redm[tid], m2);
      reds[tid] = reds[tid] * __expf(redm[tid] - mn) + s2 * __expf(m2 - mn);
      redm[tid] = mn;
    }
    __syncthreads();
  }
  const float lse = redm[0] + logf(reds[0]);

  const int i = blockIdx.x * 256 + tid;   // 500*256 == V exactly
  d_out[i] -= lse;
}

extern "C" void kernel_launch(void* const* d_in, const int* in_sizes, int n_in,
                              void* d_out, int out_size, void* d_ws, size_t ws_size,
                              hipStream_t stream) {
  const int*   ids    = (const int*)d_in[0];
  const float* hidden = (const float*)d_in[1];
  const float* emb    = (const float*)d_in[2];
  const float* W_ih   = (const float*)d_in[3];
  const float* W_hh   = (const float*)d_in[4];
  const float* b_ih   = (const float*)d_in[5];
  const float* b_hh   = (const float*)d_in[6];
  const float* W_out  = (const float*)d_in[7];
  const float* b_out  = (const float*)d_in[8];
  float* out = (float*)d_out;
  float* ws  = (float*)d_ws;

  gates_matvec<<<768, 256, 0, stream>>>(ids, hidden, emb, W_ih, W_hh, b_ih, b_hh, ws);
  logits_lse<<<K2_BLOCKS, 256, 0, stream>>>(hidden, ws, W_out, b_out, out, ws + WS_PART);
  lse_norm<<<500, 256, 0, stream>>>(out, ws + WS_PART);
}